// Round 1
// baseline (269.507 us; speedup 1.0000x reference)
//
#include <hip/hip_runtime.h>
#include <hip/hip_bf16.h>

#define B 32
#define T 512
#define U 1024
#define E 1024
#define DIN 256
#define N4 4096  // 4*U

__device__ __forceinline__ float fast_tanh(float x) {
    float e = __expf(2.0f * x);
    return 1.0f - 2.0f / (e + 1.0f);
}
__device__ __forceinline__ float fast_sigmoid(float x) {
    return 1.0f / (1.0f + __expf(-x));
}

// ---------------- K1: query partials: h[32,1024] @ Wa_w[1024,1024], k-chunks of 64
__global__ __launch_bounds__(256) void k1_qpart(const float* __restrict__ h,
                                                const float* __restrict__ Wa_w,
                                                float* __restrict__ qpart) {
    const int uc = blockIdx.x;   // 0..3
    const int kc = blockIdx.y;   // 0..15
    const int tid = threadIdx.x;
    const int k0 = kc * 64;
    __shared__ float hs[32][64];
    #pragma unroll
    for (int i = 0; i < 8; ++i) {
        int flat = i * 256 + tid;
        int b = flat >> 6, kk = flat & 63;
        hs[b][kk] = h[b * U + k0 + kk];
    }
    __syncthreads();
    const int jg = tid & 63;
    const int b0 = (tid >> 6) * 8;
    const int j = uc * 256 + jg * 4;
    float4 acc[8];
    #pragma unroll
    for (int p = 0; p < 8; ++p) acc[p] = make_float4(0.f, 0.f, 0.f, 0.f);
    const float* Wp = Wa_w + (size_t)k0 * U + j;
    #pragma unroll 4
    for (int kk = 0; kk < 64; ++kk) {
        float4 w = *(const float4*)(Wp + (size_t)kk * U);
        #pragma unroll
        for (int p = 0; p < 8; ++p) {
            float xv = hs[b0 + p][kk];
            acc[p].x += xv * w.x; acc[p].y += xv * w.y;
            acc[p].z += xv * w.z; acc[p].w += xv * w.w;
        }
    }
    #pragma unroll
    for (int p = 0; p < 8; ++p)
        *(float4*)(qpart + ((size_t)(kc * 32 + b0 + p)) * U + j) = acc[p];
}

// ---------------- K1b: reduce 16 query partials + bias
__global__ __launch_bounds__(256) void k1b_qreduce(const float* __restrict__ qpart,
                                                   const float* __restrict__ Wa_b,
                                                   float* __restrict__ query) {
    int idx = blockIdx.x * 256 + threadIdx.x;  // 32768
    int b = idx >> 10, u = idx & 1023;
    float s = Wa_b[u];
    #pragma unroll
    for (int kc = 0; kc < 16; ++kc) s += qpart[((size_t)(kc * 32 + b)) * U + u];
    query[idx] = s;
}

// ---------------- K2: logits[b,t] = sum_u tanh(query[b,u]+enc[b,t,u]) * va_w[u] + va_b
// one wave per (b,t)
__global__ __launch_bounds__(256) void k2_logits(const float* __restrict__ query,
                                                 const float* __restrict__ enc,
                                                 const float* __restrict__ va_w,
                                                 const float* __restrict__ va_b,
                                                 float* __restrict__ logits) {
    int gw = blockIdx.x * 4 + (threadIdx.x >> 6);
    int lane = threadIdx.x & 63;
    int b = gw >> 9, t = gw & 511;
    const float4* e4 = (const float4*)(enc + ((size_t)(b * T + t)) * U);
    const float4* q4 = (const float4*)(query + (size_t)b * U);
    const float4* v4 = (const float4*)va_w;
    float acc = 0.f;
    #pragma unroll
    for (int i = 0; i < 4; ++i) {
        int idx = i * 64 + lane;
        float4 e = e4[idx], q = q4[idx], v = v4[idx];
        acc += fast_tanh(e.x + q.x) * v.x;
        acc += fast_tanh(e.y + q.y) * v.y;
        acc += fast_tanh(e.z + q.z) * v.z;
        acc += fast_tanh(e.w + q.w) * v.w;
    }
    #pragma unroll
    for (int off = 32; off > 0; off >>= 1) acc += __shfl_xor(acc, off);
    if (lane == 0) logits[b * T + t] = acc + va_b[0];
}

// ---------------- K3: softmax over T per b
__global__ __launch_bounds__(256) void k3_softmax(const float* __restrict__ logits,
                                                  float* __restrict__ attn) {
    int b = blockIdx.x, tid = threadIdx.x, lane = tid & 63, w = tid >> 6;
    float l0 = logits[b * T + tid], l1 = logits[b * T + 256 + tid];
    float m = fmaxf(l0, l1);
    #pragma unroll
    for (int off = 32; off > 0; off >>= 1) m = fmaxf(m, __shfl_xor(m, off));
    __shared__ float sm[4], ss[4];
    if (lane == 0) sm[w] = m;
    __syncthreads();
    float M = fmaxf(fmaxf(sm[0], sm[1]), fmaxf(sm[2], sm[3]));
    float e0 = __expf(l0 - M), e1 = __expf(l1 - M);
    float s = e0 + e1;
    #pragma unroll
    for (int off = 32; off > 0; off >>= 1) s += __shfl_xor(s, off);
    if (lane == 0) ss[w] = s;
    __syncthreads();
    float inv = 1.0f / (ss[0] + ss[1] + ss[2] + ss[3]);
    attn[b * T + tid] = e0 * inv;
    attn[b * T + 256 + tid] = e1 * inv;
}

// ---------------- K4: context partials over t-chunks of 64
__global__ __launch_bounds__(256) void k4_ctxpart(const float* __restrict__ attn,
                                                  const float* __restrict__ speech,
                                                  float* __restrict__ ctxpart) {
    int bid = blockIdx.x;  // 1024 = 32 b * 4 ec * 8 tc
    int tc = bid & 7, ec = (bid >> 3) & 3, b = bid >> 5;
    int e = ec * 256 + threadIdx.x;
    int t0 = tc * 64;
    const float* sp = speech + ((size_t)(b * T + t0)) * E + e;
    const float* at = attn + b * T + t0;
    float acc = 0.f;
    #pragma unroll 4
    for (int tt = 0; tt < 64; ++tt) acc += at[tt] * sp[(size_t)tt * E];
    ctxpart[((size_t)(tc * 32 + b)) * E + e] = acc;
}

// ---------------- K4b: reduce 8 context partials
__global__ __launch_bounds__(256) void k4b_ctxreduce(const float* __restrict__ ctxpart,
                                                     float* __restrict__ context) {
    int idx = blockIdx.x * 256 + threadIdx.x;  // 32768
    int b = idx >> 10, e = idx & 1023;
    float s = 0.f;
    #pragma unroll
    for (int tc = 0; tc < 8; ++tc) s += ctxpart[((size_t)(tc * 32 + b)) * E + e];
    context[idx] = s;
}

// ---------------- K5: z partials: [x;ctx;h][32,2304] @ [Wk;Wr][2304,4096], k-chunks of 128
__global__ __launch_bounds__(256) void k5_zpart(const float* __restrict__ xin,
                                                const float* __restrict__ ctx,
                                                const float* __restrict__ h,
                                                const float* __restrict__ Wk,
                                                const float* __restrict__ Wr,
                                                float* __restrict__ zpart) {
    const int jc = blockIdx.x;  // 0..15
    const int kc = blockIdx.y;  // 0..17
    const int tid = threadIdx.x;
    const int k0 = kc * 128;
    __shared__ float xs[32][128];
    #pragma unroll
    for (int i = 0; i < 16; ++i) {
        int flat = i * 256 + tid;
        int b = flat >> 7, kk = flat & 127;
        int k = k0 + kk;
        float v;
        if (k < DIN)          v = xin[b * DIN + k];
        else if (k < DIN + E) v = ctx[b * E + (k - DIN)];
        else                  v = h[b * U + (k - DIN - E)];
        xs[b][kk] = v;
    }
    __syncthreads();
    const int jg = tid & 63;
    const int b0 = (tid >> 6) * 8;
    const int j = jc * 256 + jg * 4;
    const float* Wrow = (k0 < DIN + E) ? (Wk + (size_t)k0 * N4 + j)
                                       : (Wr + (size_t)(k0 - (DIN + E)) * N4 + j);
    float4 acc[8];
    #pragma unroll
    for (int p = 0; p < 8; ++p) acc[p] = make_float4(0.f, 0.f, 0.f, 0.f);
    #pragma unroll 4
    for (int kk = 0; kk < 128; ++kk) {
        float4 w = *(const float4*)(Wrow + (size_t)kk * N4);
        #pragma unroll
        for (int p = 0; p < 8; ++p) {
            float xv = xs[b0 + p][kk];
            acc[p].x += xv * w.x; acc[p].y += xv * w.y;
            acc[p].z += xv * w.z; acc[p].w += xv * w.w;
        }
    }
    #pragma unroll
    for (int p = 0; p < 8; ++p)
        *(float4*)(zpart + ((size_t)(kc * 32 + b0 + p)) * N4 + j) = acc[p];
}

// ---------------- K6: reduce 18 z partials + bias, LSTM gates, write outputs
__global__ __launch_bounds__(256) void k6_gates(const float* __restrict__ zpart,
                                                const float* __restrict__ bias,
                                                const float* __restrict__ c,
                                                float* __restrict__ out) {
    int idx = blockIdx.x * 256 + threadIdx.x;  // 32768 = b*1024+u
    int b = idx >> 10, u = idx & 1023;
    float zi = bias[u], zf = bias[U + u], zg = bias[2 * U + u], zo = bias[3 * U + u];
    for (int kc = 0; kc < 18; ++kc) {
        const float* zp = zpart + ((size_t)(kc * 32 + b)) * N4;
        zi += zp[u]; zf += zp[U + u]; zg += zp[2 * U + u]; zo += zp[3 * U + u];
    }
    float cn = fast_sigmoid(zf) * c[idx] + fast_sigmoid(zi) * fast_tanh(zg);
    float hn = fast_sigmoid(zo) * fast_tanh(cn);
    out[idx] = hn;
    out[32768 + idx] = hn;
    out[65536 + idx] = cn;
}

extern "C" void kernel_launch(void* const* d_in, const int* in_sizes, int n_in,
                              void* d_out, int out_size, void* d_ws, size_t ws_size,
                              hipStream_t stream) {
    const float* inputs = (const float*)d_in[0];
    const float* h      = (const float*)d_in[1];
    const float* c      = (const float*)d_in[2];
    const float* speech = (const float*)d_in[3];
    const float* enc    = (const float*)d_in[4];
    const float* Wa_w   = (const float*)d_in[5];
    const float* Wa_b   = (const float*)d_in[6];
    const float* va_w   = (const float*)d_in[7];
    const float* va_b   = (const float*)d_in[8];
    const float* Wk     = (const float*)d_in[9];
    const float* Wr     = (const float*)d_in[10];
    const float* bias   = (const float*)d_in[11];
    float* out = (float*)d_out;
    float* ws  = (float*)d_ws;

    float* query   = ws;             // 32768
    float* qpart   = ws + 32768;     // 16*32*1024 = 524288
    float* logits  = ws + 557056;    // 16384
    float* attn    = ws + 573440;    // 16384
    float* ctxpart = ws + 589824;    // 8*32*1024 = 262144
    float* context = ws + 851968;    // 32768
    float* zpart   = ws + 884736;    // 18*32*4096 = 2359296  (end 3244032 floats ~ 13 MB)

    k1_qpart<<<dim3(4, 16), 256, 0, stream>>>(h, Wa_w, qpart);
    k1b_qreduce<<<128, 256, 0, stream>>>(qpart, Wa_b, query);
    k2_logits<<<4096, 256, 0, stream>>>(query, enc, va_w, va_b, logits);
    k3_softmax<<<32, 256, 0, stream>>>(logits, attn);
    k4_ctxpart<<<1024, 256, 0, stream>>>(attn, speech, ctxpart);
    k4b_ctxreduce<<<128, 256, 0, stream>>>(ctxpart, context);
    k5_zpart<<<dim3(16, 18), 256, 0, stream>>>(inputs, context, h, Wk, Wr, zpart);
    k6_gates<<<128, 256, 0, stream>>>(zpart, bias, c, out);
}